// Round 10
// baseline (154.464 us; speedup 1.0000x reference)
//
#include <hip/hip_runtime.h>
#include <hip/hip_fp8.h>

#define P 196
#define NN 32
#define MARGIN 0.5f
#define NCH 12            // K-chunks of 64 int8 elements
#define APIECES 896       // full-A: 224 rows * 4 pieces (16 B) per chunk
#define CHB (APIECES * 16)             // 14336 bytes per image-chunk
#define HPIECES 448                    // half (112 rows) of A or B: 448 pieces
#define HBYTES (HPIECES * 16)          // 7168 B
#define BUFB (2 * HBYTES)              // 14336 B: A-half + B-half per buffer
#define YBYTES (64 * NCH * CHB)        // 11,010,048 B
#define SCR_N (1520 * 2 * 112)         // colmax scratch entries (340,480)

#define QS 400.0f                      // int8 quant scale: x_int = round(x*QS)
#define INV_QS2 (1.0f / (QS * QS))     // sim = int_dot * INV_QS2

typedef int   intx4   __attribute__((ext_vector_type(4)));   // 16 B = one K=64 i8 frag

typedef __attribute__((address_space(1))) const unsigned char g_u8;
typedef __attribute__((address_space(3))) unsigned char l_u8;

// Workspace layout:
//   [0, YBYTES)          : Y, int8 chunk-major swizzled (HW-verified geometry,
//                          R8/R16): piece(img,c,r,kg') at (img*12+c)*14336 +
//                          (r*4+kg')*16, kg'=kg^((r>>1)&3).
//   [YBYTES, +SCR_N*4)   : colmax scratch, uint-encoded float keys
//                          key = bits(sim + 2.0f)  (sim in [-1,1] -> positive
//                          float -> IEEE bits monotone). Zeroed by norm_kernel
//                          each iteration (0 decodes to -2.0 = -inf sentinel;
//                          ws 0xAA poison would otherwise dominate the max).

// ---------------------------------------------------------------------------
// Kernel 1 (R16-verified + scratch zeroing): normalize + int8 quantize.
// ---------------------------------------------------------------------------
__global__ __launch_bounds__(512) void norm_kernel(const float* __restrict__ nrm,
                                                   const float* __restrict__ dft,
                                                   unsigned char* __restrict__ Y,
                                                   float* __restrict__ out) {
    if (blockIdx.x == 0 && threadIdx.x == 0) out[0] = 0.0f;
    {   // zero the colmax scratch (pair's atomicMax needs a clean sentinel)
        unsigned gidx = blockIdx.x * 512 + threadIdx.x;
        if (gidx < SCR_N) ((unsigned*)(Y + YBYTES))[gidx] = 0u;
    }
    __shared__ uint2 rowbuf[8][100];             // 96 groups of 8 bytes per row

    int img  = blockIdx.x / 28;
    int rg   = blockIdx.x % 28;
    int wave = threadIdx.x >> 6;
    int lane = threadIdx.x & 63;
    int p = rg * 8 + wave;

    if (p < P) {
        const float* src = (img < NN) ? nrm + ((size_t)img * P + p) * 768
                                      : dft + ((size_t)(img - NN) * P + p) * 768;
        float4 a0 = *(const float4*)(src + lane * 8);
        float4 a1 = *(const float4*)(src + lane * 8 + 4);
        float4 b0 = {0,0,0,0}, b1 = {0,0,0,0};
        float ss = a0.x*a0.x + a0.y*a0.y + a0.z*a0.z + a0.w*a0.w
                 + a1.x*a1.x + a1.y*a1.y + a1.z*a1.z + a1.w*a1.w;
        if (lane < 32) {
            b0 = *(const float4*)(src + 512 + lane * 8);
            b1 = *(const float4*)(src + 512 + lane * 8 + 4);
            ss += b0.x*b0.x + b0.y*b0.y + b0.z*b0.z + b0.w*b0.w
                + b1.x*b1.x + b1.y*b1.y + b1.z*b1.z + b1.w*b1.w;
        }
        #pragma unroll
        for (int o = 32; o > 0; o >>= 1) ss += __shfl_xor(ss, o);
        float qsc = QS / (sqrtf(ss) + 1e-8f);    // normalize * quant scale

        auto qi = [&](float f) -> unsigned {     // fp32 -> clamped int8 byte
            float v = f * qsc;
            v = fminf(fmaxf(v, -127.0f), 127.0f);
            return (unsigned)((int)rintf(v) & 255);
        };
        auto pack8 = [&](float4 x0, float4 x1) {
            uint2 g;
            g.x = qi(x0.x) | (qi(x0.y) << 8) | (qi(x0.z) << 16) | (qi(x0.w) << 24);
            g.y = qi(x1.x) | (qi(x1.y) << 8) | (qi(x1.z) << 16) | (qi(x1.w) << 24);
            return g;
        };
        rowbuf[wave][lane] = pack8(a0, a1);                     // groups 0..63
        if (lane < 32) rowbuf[wave][64 + lane] = pack8(b0, b1); // groups 64..95
    }
    __syncthreads();

    int idx = threadIdx.x;
    if (idx < 384) {
        int c = idx >> 5, r = (idx >> 2) & 7, kgp = idx & 3;
        int pr = rg * 8 + r;
        if (pr < P) {
            int kg = kgp ^ ((pr >> 1) & 3);
            uint2 lo = rowbuf[r][c * 8 + kg];        // k-low half
            uint2 hi = rowbuf[r][c * 8 + 4 + kg];    // k-high half
            uint4 o; o.x = lo.x; o.y = lo.y; o.z = hi.x; o.w = hi.y;
            *(uint4*)(Y + (size_t)(img * NCH + c) * CHB + (pr * 4 + kgp) * 16) = o;
        }
    }
}

// ---------------------------------------------------------------------------
// Pair ordering table (compile-time): macro-tiled for L2 locality (R10,
// verified). v[b] = ia | (ja<<8), ja global index.
// ---------------------------------------------------------------------------
struct PairTab { unsigned short v[1520]; };
static constexpr PairTab mk_tab() {
    PairTab t{};
    int n = 0;
    for (int gi = 0; gi < 4; ++gi)                  // nn: 496 pairs, i<j
        for (int gj = gi; gj < 4; ++gj)
            for (int i = gi*8; i < gi*8 + 8; ++i) {
                int j0 = (gi == gj) ? i + 1 : gj*8;
                for (int j = j0; j < gj*8 + 8; ++j)
                    t.v[n++] = (unsigned short)(i | (j << 8));
            }
    for (int gi = 0; gi < 4; ++gi)                  // nd: 1024 pairs
        for (int gd = 0; gd < 4; ++gd)
            for (int i = gi*8; i < gi*8 + 8; ++i)
                for (int d = gd*8; d < gd*8 + 8; ++d)
                    t.v[n++] = (unsigned short)(i | ((32 + d) << 8));
    return t;
}
__constant__ PairTab PTAB = mk_tab();

// ---------------------------------------------------------------------------
// Kernel 2 (R18): 112x112 BLOCKS FOR CO-RESIDENCY (occupancy attack).
//   R13/R14/R15/R17 all ~nil/negative => pair is critical-path-bound, not
//   pipe-bound; only more co-resident waves can fill the per-phase bubbles.
//   Blocks shrink 224x112 -> 112x112 (grid 6080 = pair x qh x ah):
//     * acc <=32, frags <=24, arch ~80 -> __launch_bounds__(512,6) (85 cap);
//     * LDS buffer (448A+448B pieces) = 14336 B, x3 = 43008 B
//       -> 3 blocks/CU x 8 waves = 24 waves/CU (was 16).
//   Max-over-p now spans 2 blocks (ah=0/1) -> epilogue does global atomicMax
//   of key=bits(sim+2.0f) into scratch [1520][2][112]; loss_kernel (3rd
//   launch) decodes, masks q>=196, sums. MFMA total unchanged; A re-read x2
//   (L3-resident, R17 showed byte-traffic is not binding).
//   Skeleton (3-buffer counted vmcnt, swizzle, i8 MFMA, DMA split) = R16.
// Per-wave rects (W&3 -> B-group {0,2,4,6}x{2,2,2,1}; W<4 -> A-group 0):
//   ah=0: A{4,3} over tiles 0-6;  ah=1: A{3,3} over tiles 7-12.
// ---------------------------------------------------------------------------
template<int W, int AH>
__device__ void wave_worker(uint4* tiles, const unsigned char* gA,
                            const unsigned char* gB, int lane,
                            unsigned* scr, int pairq) {
    constexpr int BS = (W & 3) * 2;
    constexpr int BC = ((W & 3) == 3) ? 1 : 2;
    constexpr int AS = (W < 4) ? 0 : (AH ? 3 : 4);
    constexpr int AC = (W < 4) ? (AH ? 3 : 4) : 3;
    constexpr int GT0 = AH ? 7 : 0;       // global A-tile base
    constexpr int DA = (W < 6) ? 2 : 1;   // own DMAs per chunk (i = W, W+8<14)

    int r16  = lane & 15;
    int quad = lane >> 4;                 // 0..3 : k-group of 8
    int sw   = quad ^ ((r16 >> 1) & 3);   // XOR swizzle (verified conflict-free)
    int fofs = (r16 * 4 + sw) * 16;       // per-lane frag byte offset
    l_u8* lds0 = (l_u8*)tiles;

    intx4 acc[AC][BC];
    #pragma unroll
    for (int a = 0; a < AC; ++a)
        #pragma unroll
        for (int b = 0; b < BC; ++b)
            acc[a][b] = (intx4){0, 0, 0, 0};

    // 14 DMAs/chunk over 8 waves: i<7 = A-half pieces, i>=7 = B-half pieces.
    auto stage = [&](const unsigned char* ga, const unsigned char* gb, l_u8* ldsb) {
        #pragma unroll
        for (int u = 0; u < 2; ++u) {
            if (W + 8 * u < 14) {
                int i = W + 8 * u;
                const unsigned char* g = (i < 7) ? ga + (i * 64 + lane) * 16
                                                 : gb + ((i - 7) * 64 + lane) * 16;
                __builtin_amdgcn_global_load_lds((const g_u8*)g, ldsb + i * 1024, 16, 0, 0);
            }
        }
    };

    stage(gA, gB, lds0);         gA += CHB;  gB += CHB;   // chunk 0 -> buf0
    stage(gA, gB, lds0 + BUFB);  gA += CHB;  gB += CHB;   // chunk 1 -> buf1

    const char* abp = (const char*)tiles + fofs;            // A at buf+0
    const char* bbp = (const char*)tiles + HBYTES + fofs;   // B at buf+7168

    for (int cb = 0; cb < NCH; cb += 3) {
        #pragma unroll
        for (int cc = 0; cc < 3; ++cc) {
            int c = cb + cc;
            // counted wait: drain own chunk-c DMAs, keep chunk c+1's in
            // flight across the barrier (proven R13/R16 skeleton).
            if (c == NCH - 1) __builtin_amdgcn_s_waitcnt(0xF70);       // vmcnt(0)
            else              __builtin_amdgcn_s_waitcnt(0xF70 | DA);  // vmcnt(DA)
            __builtin_amdgcn_s_barrier();
            __builtin_amdgcn_sched_barrier(0);   // pin: no ds_read above barrier

            intx4 afr[AC], bfr[BC];
            #pragma unroll
            for (int a = 0; a < AC; ++a)
                afr[a] = *(const intx4*)(abp + cc * BUFB + (AS + a) * 1024);
            #pragma unroll
            for (int b = 0; b < BC; ++b)
                bfr[b] = *(const intx4*)(bbp + cc * BUFB + (BS + b) * 1024);

            if (c + 2 < NCH) {                   // stage chunk c+2 -> buf[(c+2)%3]
                stage(gA, gB, lds0 + ((cc + 2) % 3) * BUFB);
                gA += CHB;  gB += CHB;
            }

            __builtin_amdgcn_s_setprio(1);
            #pragma unroll
            for (int a = 0; a < AC; ++a)
                #pragma unroll
                for (int b = 0; b < BC; ++b)
                    acc[a][b] = __builtin_amdgcn_mfma_i32_16x16x64_i8(
                        afr[a], bfr[b], acc[a][b], 0, 0, 0);
            __builtin_amdgcn_s_setprio(0);
        }
    }

    // Epilogue: per-column max (int, exact) -> float key -> global atomicMax.
    // C/D: col q = lane&15, row p = (GT0+AS+a)*16 + quad*4 + r.
    #pragma unroll
    for (int b = 0; b < BC; ++b) {
        int m = (int)0x80000000;
        #pragma unroll
        for (int a = 0; a < AC; ++a) {
            int pbase = (GT0 + AS + a) * 16 + quad * 4;
            #pragma unroll
            for (int r = 0; r < 4; ++r)
                if (pbase + r < P) m = max(m, acc[a][b][r]);
        }
        m = max(m, __shfl_xor(m, 16));
        m = max(m, __shfl_xor(m, 32));
        if (quad == 0) {
            float key = (float)m * INV_QS2 + 2.0f;   // sim+2 > 0: bits monotone
            atomicMax(scr + pairq * 112 + (BS + b) * 16 + r16,
                      __float_as_uint(key));
        }
    }
}

__global__ __launch_bounds__(512, 6) void pair_kernel(const unsigned char* __restrict__ Y,
                                                      float* __restrict__ out) {
    __shared__ uint4 tiles[3 * HPIECES * 2];   // 43008 B (3 x 14336)

    int bx = blockIdx.x;
    int l  = (bx & 7) * 760 + (bx >> 3);   // XCD k owns logical [760k, 760k+760)
    int b  = l >> 2;                 // pair index (macro-tiled order)
    int qh = (l >> 1) & 1;           // q-half (B cols)
    int ah = l & 1;                  // A-half (rows); adjacent l share A/B tiles
    unsigned short pk = PTAB.v[b];
    int ia = pk & 255;
    int ja = pk >> 8;

    int tid  = threadIdx.x;
    int lane = tid & 63;
    int wave = tid >> 6;             // 0..7

    const unsigned char* gA = Y + (size_t)ia * (NCH * CHB) + ah * HBYTES;
    const unsigned char* gB = Y + (size_t)ja * (NCH * CHB) + qh * HBYTES;
    unsigned* scr = (unsigned*)(Y + YBYTES);
    int pairq = b * 2 + qh;

    if (ah == 0) {
        switch (wave) {
            case 0: wave_worker<0,0>(tiles, gA, gB, lane, scr, pairq); break;
            case 1: wave_worker<1,0>(tiles, gA, gB, lane, scr, pairq); break;
            case 2: wave_worker<2,0>(tiles, gA, gB, lane, scr, pairq); break;
            case 3: wave_worker<3,0>(tiles, gA, gB, lane, scr, pairq); break;
            case 4: wave_worker<4,0>(tiles, gA, gB, lane, scr, pairq); break;
            case 5: wave_worker<5,0>(tiles, gA, gB, lane, scr, pairq); break;
            case 6: wave_worker<6,0>(tiles, gA, gB, lane, scr, pairq); break;
            default: wave_worker<7,0>(tiles, gA, gB, lane, scr, pairq); break;
        }
    } else {
        switch (wave) {
            case 0: wave_worker<0,1>(tiles, gA, gB, lane, scr, pairq); break;
            case 1: wave_worker<1,1>(tiles, gA, gB, lane, scr, pairq); break;
            case 2: wave_worker<2,1>(tiles, gA, gB, lane, scr, pairq); break;
            case 3: wave_worker<3,1>(tiles, gA, gB, lane, scr, pairq); break;
            case 4: wave_worker<4,1>(tiles, gA, gB, lane, scr, pairq); break;
            case 5: wave_worker<5,1>(tiles, gA, gB, lane, scr, pairq); break;
            case 6: wave_worker<6,1>(tiles, gA, gB, lane, scr, pairq); break;
            default: wave_worker<7,1>(tiles, gA, gB, lane, scr, pairq); break;
        }
    }
}

// ---------------------------------------------------------------------------
// Kernel 3 (new): decode colmax scratch, mask pad cols, sum the loss.
// One block per pair; 224 cols across 2 q-halves.
// ---------------------------------------------------------------------------
__global__ __launch_bounds__(256) void loss_kernel(const unsigned char* __restrict__ Y,
                                                   float* __restrict__ out) {
    __shared__ float redp[4];
    const unsigned* scr = (const unsigned*)(Y + YBYTES);
    int b    = blockIdx.x;
    int tid  = threadIdx.x;
    int lane = tid & 63;
    int wave = tid >> 6;

    float contrib = 0.f;
    if (tid < P) {                                   // q >= 196 are pad cols
        int qh = (tid < 112) ? 0 : 1;
        int lq = tid - qh * 112;
        float cm = __uint_as_float(scr[(b * 2 + qh) * 112 + lq]) - 2.0f;
        contrib = (b < 496) ? (1.0f - cm) * (1.0f / (496.0f * 196.0f))
                            : fmaxf(cm - MARGIN, 0.0f) * (1.0f / (1024.0f * 196.0f));
    }
    #pragma unroll
    for (int o = 32; o > 0; o >>= 1) contrib += __shfl_down(contrib, o);
    if (lane == 0) redp[wave] = contrib;
    __syncthreads();
    if (tid == 0)
        atomicAdd(out, redp[0] + redp[1] + redp[2] + redp[3]);
}

// ---------------------------------------------------------------------------
extern "C" void kernel_launch(void* const* d_in, const int* in_sizes, int n_in,
                              void* d_out, int out_size, void* d_ws, size_t ws_size,
                              hipStream_t stream) {
    const float* nrm = (const float*)d_in[0];   // [32,196,768] fp32
    const float* dft = (const float*)d_in[1];   // [32,196,768] fp32
    float* out = (float*)d_out;                 // scalar fp32
    unsigned char* Y = (unsigned char*)d_ws;    // int8 Y (10.5 MB) + scratch (1.36 MB)

    norm_kernel<<<64 * 28, 512, 0, stream>>>(nrm, dft, Y, out);
    pair_kernel<<<4 * 1520, 512, 0, stream>>>(Y, out);
    loss_kernel<<<1520, 256, 0, stream>>>(Y, out);
}